// Round 4
// baseline (488.092 us; speedup 1.0000x reference)
//
#include <hip/hip_runtime.h>

#define NELEM 500000
#define NDOF 500000
#define HID 64

typedef _Float16 half2v __attribute__((ext_vector_type(2)));
typedef _Float16 half8v __attribute__((ext_vector_type(8)));
typedef float float4v __attribute__((ext_vector_type(4)));

// lambda = 2*log2(e): prescaled into W1,b1,W2,b2 so tanh needs no multiply.
#define LAM 2.885390081777927f

__device__ __forceinline__ half2v pk(float a, float b) {
    return __builtin_bit_cast(half2v, __builtin_amdgcn_cvt_pkrtz(a, b));
}
// tanh(z) with y = LAM*z prescaled. exp2(+-inf) saturates correctly.
__device__ __forceinline__ float tanh2(float y) {
    float e = __builtin_amdgcn_exp2f(y);
    float r = __builtin_amdgcn_rcpf(e + 1.0f);
    return fmaf(-2.0f, r, 1.0f);
}
__device__ __forceinline__ float fdot2(half2v a, half2v b, float c) {
    return __builtin_amdgcn_fdot2(a, b, c, false);
}

// ds_swizzle BitMode: src = ((lane&AND)|OR)^XOR within 32-lane halves.
//   quad broadcast j: 0x1C,0x3C,0x5C,0x7C ; xor16: 0x401F
#define SWZF(x, pat) __builtin_bit_cast(float, \
    __builtin_amdgcn_ds_swizzle(__builtin_bit_cast(int, (x)), (pat)))

// ---- setup kernel: pack per-lane weight fragments into workspace ----
// Layout (uint4 units, [frag][lane]):
//   0..3  : w1p  (16 half2 = LAM*W1 cols for this lane's quad)
//   4..7  : b1v  (16 f32  = LAM*b1)
//   8..15 : bf[t][f] (half8 W2 fragments, frag idx = 8+2t+f)
__global__ __launch_bounds__(64, 1) void pack_weights(
    const float* __restrict__ W1, const float* __restrict__ b1,
    const float* __restrict__ W2, uint4* __restrict__ ws)
{
    const int lane = threadIdx.x & 63;
    const int quad = lane >> 4, l15 = lane & 15;
    union { uint4 q[4]; uint u[16]; } WU;
    union { uint4 q[4]; float f[16]; } BU;
#pragma unroll
    for (int f = 0; f < 2; f++)
#pragma unroll
        for (int j = 0; j < 8; j++) {
            const int k = f * 32 + quad * 8 + j;
            WU.u[f * 8 + j] = __builtin_bit_cast(uint, pk(LAM * W1[k], LAM * W1[HID + k]));
            BU.f[f * 8 + j] = LAM * b1[k];
        }
#pragma unroll
    for (int i = 0; i < 4; i++) {
        ws[i * 64 + lane] = WU.q[i];
        ws[(4 + i) * 64 + lane] = BU.q[i];
    }
#pragma unroll
    for (int t = 0; t < 4; t++)
#pragma unroll
        for (int f = 0; f < 2; f++) {
            union { uint4 q; uint u[4]; } T;
#pragma unroll
            for (int jj = 0; jj < 4; jj++) {
                const int k0 = f * 32 + quad * 8 + 2 * jj;
                const int n  = t * 16 + l15;
                T.u[jj] = __builtin_bit_cast(uint,
                    pk(LAM * W2[k0 * HID + n], LAM * W2[(k0 + 1) * HID + n]));
            }
            ws[(8 + 2 * t + f) * 64 + lane] = T.q;
        }
}

// one layer-2/3 tile step: C=b2 -> 2 MFMA -> tanh -> layer-3 partials
#define TSTEP(tt, qa, qb) do { \
    const float4v b2v = *(const float4v*)&b2t[(quad + zr) * 16 + (tt) * 4]; \
    float4v c = b2v; \
    c = __builtin_amdgcn_mfma_f32_16x16x32_f16(__builtin_bit_cast(half8v, qa), B0.v, c, 0, 0, 0); \
    c = __builtin_amdgcn_mfma_f32_16x16x32_f16(__builtin_bit_cast(half8v, qb), B1.v, c, 0, 0, 0); \
    const float4v a4 = *(const float4v*)&w3at[(quad + zr) * 16 + (tt) * 4]; \
    const float4v b4 = *(const float4v*)&w3bt[(quad + zr) * 16 + (tt) * 4]; \
    _Pragma("unroll") \
    for (int reg = 0; reg < 4; reg++) { \
        const float h = tanh2(c[reg]); \
        s0 = fmaf(h, a4[reg], s0); \
        s1 = fmaf(h, b4[reg], s1); \
    } \
} while (0)

// 2-elements-per-thread 3-phase GP kernel (128 elems / 512 GP-rows per
// block). Weight fragments come packed from ws (no per-thread pk VALU);
// bf streamed per rt from L1 with an opaque-zero guard against LICM
// re-hoisting into held registers (round-1 spill lesson).
__global__ __launch_bounds__(256, 6) void fem_force_kernel(
    const float* __restrict__ u, const float* __restrict__ B,
    const float* __restrict__ Jacc, const float* __restrict__ gp_w,
    const int* __restrict__ conn, const float* __restrict__ weight1,
    const float* __restrict__ scales_inp, const float* __restrict__ limits_inp,
    const float* __restrict__ scales_grad, const float* __restrict__ limits_grad,
    const float* __restrict__ b2, const float* __restrict__ W3,
    const float* __restrict__ b3, const uint4* __restrict__ wt,
    float* __restrict__ F)
{
    __shared__ uint sX[512];        // packed-f16 (x0,x1) per GP-row
    __shared__ uint sG[512];        // packed-f16 (p,q)  per GP-row
    __shared__ uint sB[512][9];     // packed-f16 (P[j],Q[j]) j=0..7, pad
    __shared__ __align__(16) float b2t[64];
    __shared__ __align__(16) float w3at[64];
    __shared__ __align__(16) float w3bt[64];

    const int tid  = threadIdx.x;
    const int lane = tid & 63;
    const int wv   = tid >> 6;
    const int quad = lane >> 4;
    const int l15  = lane & 15;
    const int g    = tid & 3;        // gauss point of this thread
    const int m    = tid >> 2;       // element slot within group

    // stage b2 / W3 broadcast tables (index: i = quad*16 + t*4 + reg)
    if (tid < 192) {
        const int i  = tid & 63;
        const int it = (i >> 2) & 3, iq = i >> 4, ir = i & 3;
        const int n  = it * 16 + iq * 4 + ir;
        if (tid < 64)       b2t[i]  = LAM * b2[n];
        else if (tid < 128) w3at[i] = W3[2 * n];
        else                w3bt[i] = W3[2 * n + 1];
    }

    const float SQ23 = 0.816496580927726f;
    const float si0 = scales_inp[0], si1 = scales_inp[1];
    const float li0 = limits_inp[0], li1 = limits_inp[1];
    const float isg0 = 1.0f / scales_grad[0], isg1 = 1.0f / scales_grad[1];
    const float b30c = b3[0] - limits_grad[0];
    const float b31c = b3[1] - limits_grad[1];

    // ---- phase 1: two elements' strain invariants -> P,Q + x to LDS ----
    int nds[2];
#pragma unroll
    for (int z = 0; z < 2; z++) {
        const int e   = blockIdx.x * 128 + z * 64 + m;
        const int row = z * 256 + tid;
        uint xw = 0u; int nd = 0;
        if (e < NELEM) {
            nd = conn[4 * e + g];
            const float2 uu  = *(const float2*)(u + 2 * nd);
            const float2 wv2 = *(const float2*)(weight1 + 2 * nd);
            const float vx = wv2.x * uu.x, vy = wv2.y * uu.y;
            float ue[8];
            ue[0] = SWZF(vx, 0x1C); ue[1] = SWZF(vy, 0x1C);
            ue[2] = SWZF(vx, 0x3C); ue[3] = SWZF(vy, 0x3C);
            ue[4] = SWZF(vx, 0x5C); ue[5] = SWZF(vy, 0x5C);
            ue[6] = SWZF(vx, 0x7C); ue[7] = SWZF(vy, 0x7C);

            float Bg[24];
            const float4* Bp = (const float4*)(B + (size_t)(e * 4 + g) * 24);
#pragma unroll
            for (int t2 = 0; t2 < 6; t2++) {
                const float4 v = Bp[t2];
                Bg[4 * t2 + 0] = v.x; Bg[4 * t2 + 1] = v.y;
                Bg[4 * t2 + 2] = v.z; Bg[4 * t2 + 3] = v.w;
            }
            float s0 = 0.f, s1 = 0.f, s2 = 0.f;
#pragma unroll
            for (int j = 0; j < 8; j++) {
                s0 = fmaf(Bg[j],      ue[j], s0);
                s1 = fmaf(Bg[8 + j],  ue[j], s1);
                s2 = fmaf(Bg[16 + j], ue[j], s2);
            }
            const float ev  = s0 + s1;
            const float ev3 = ev * (1.0f / 3.0f);
            const float d00 = s0 - ev3, d11 = s1 - ev3, d22 = -ev3, d01 = 0.5f * s2;
            const float det = sqrtf(d00 * d00 + d11 * d11 + d22 * d22 + 2.0f * d01 * d01);
            const float rd  = __builtin_amdgcn_rcpf(det);
            const float es  = det * SQ23;
            const float wgt = Jacc[4 * e + g] * gp_w[g];
            const float sc  = SQ23 * rd * wgt;
            const float c00 = sc * d00, c11 = sc * d11, c01 = sc * d01;
#pragma unroll
            for (int j = 0; j < 8; j++) {
                const float P = wgt * (Bg[j] + Bg[8 + j]);
                const float Q = fmaf(c00, Bg[j], fmaf(c11, Bg[8 + j], c01 * Bg[16 + j]));
                sB[row][j] = __builtin_bit_cast(uint, pk(P, Q));
            }
            xw = __builtin_bit_cast(uint, pk(fmaf(ev, si0, li0), fmaf(es, si1, li1)));
        }
        sX[row] = xw;
        nds[z] = nd;
    }
    __syncthreads();

    // ---- held layer-1 fragments: 8 coalesced dwordx4, zero pack VALU ----
    union { uint4 q[4]; uint u[16]; } W1U;
    union { uint4 q[4]; float f[16]; } B1U;
#pragma unroll
    for (int i = 0; i < 4; i++) {
        W1U.q[i] = wt[i * 64 + lane];
        B1U.q[i] = wt[(4 + i) * 64 + lane];
    }

    // ---- phase 2: 8 MFMA tiles per wave (rows wv*128 .. wv*128+127) ----
    int zr = 0;                      // opaque zero: defeats LICM/CSE
#pragma unroll 1
    for (int rt = 0; rt < 8; rt++) {
        asm volatile("" : "+v"(zr));
        const int tb = wv * 128 + rt * 16;
        const half2v xp = __builtin_bit_cast(half2v, sX[tb + l15 + zr]);

        // stream first-half bf fragments (L1-resident after rt=0)
        uint4 bq0 = wt[(8 + 0) * 64 + lane + zr];
        uint4 bq1 = wt[(8 + 1) * 64 + lane + zr];
        uint4 bq2 = wt[(8 + 2) * 64 + lane + zr];
        uint4 bq3 = wt[(8 + 3) * 64 + lane + zr];

        // layer 1 -> h1 fragments (B operand of swapped MFMA)
        union { half8v v; uint uu[4]; } B0, B1;
#pragma unroll
        for (int jj = 0; jj < 4; jj++) {
            const float t0 = tanh2(fdot2(xp, __builtin_bit_cast(half2v, W1U.u[2 * jj]),     B1U.f[2 * jj]));
            const float t1 = tanh2(fdot2(xp, __builtin_bit_cast(half2v, W1U.u[2 * jj + 1]), B1U.f[2 * jj + 1]));
            const float t2 = tanh2(fdot2(xp, __builtin_bit_cast(half2v, W1U.u[8 + 2 * jj]),     B1U.f[8 + 2 * jj]));
            const float t3 = tanh2(fdot2(xp, __builtin_bit_cast(half2v, W1U.u[8 + 2 * jj + 1]), B1U.f[8 + 2 * jj + 1]));
            B0.uu[jj] = __builtin_bit_cast(uint, pk(t0, t1));
            B1.uu[jj] = __builtin_bit_cast(uint, pk(t2, t3));
        }

        float s0 = 0.f, s1 = 0.f;
        TSTEP(0, bq0, bq1);
        TSTEP(1, bq2, bq3);
        const uint4 bq4 = wt[(8 + 4) * 64 + lane + zr];
        const uint4 bq5 = wt[(8 + 5) * 64 + lane + zr];
        const uint4 bq6 = wt[(8 + 6) * 64 + lane + zr];
        const uint4 bq7 = wt[(8 + 7) * 64 + lane + zr];
        TSTEP(2, bq4, bq5);
        TSTEP(3, bq6, bq7);

        // packed f16 reduce over the 4 quads (hidden axis): xor16, xor32
        uint su = __builtin_bit_cast(uint, pk(s0, s1));
        const uint sw = (uint)__builtin_amdgcn_ds_swizzle((int)su, 0x401F);
        half2v sp = __builtin_bit_cast(half2v, su) + __builtin_bit_cast(half2v, sw);
        const uint s2u = (uint)__shfl_xor((int)__builtin_bit_cast(uint, sp), 32, 64);
        sp = sp + __builtin_bit_cast(half2v, s2u);
        if (quad == 0) {
            const float p = ((float)sp[0] + b30c) * isg0;
            const float q = ((float)sp[1] + b31c) * isg1;
            sG[tb + l15] = __builtin_bit_cast(uint, pk(p, q));
        }
    }
    __syncthreads();

    // ---- phase 3: EP pair via fdot2 of (p,q)x(P,Q), 2 atomics/elem ----
#pragma unroll
    for (int z = 0; z < 2; z++) {
        const int e = blockIdx.x * 128 + z * 64 + m;
        if (e < NELEM) {
            const int rb = z * 256 + (tid & ~3);
            float a = 0.f, b = 0.f;
#pragma unroll
            for (int gp = 0; gp < 4; gp++) {
                const half2v pq = __builtin_bit_cast(half2v, sG[rb + gp]);
                const half2v w0 = __builtin_bit_cast(half2v, sB[rb + gp][2 * g]);
                const half2v w1 = __builtin_bit_cast(half2v, sB[rb + gp][2 * g + 1]);
                a = fdot2(pq, w0, a);
                b = fdot2(pq, w1, b);
            }
            atomicAdd(&F[2 * nds[z]],     a);
            atomicAdd(&F[2 * nds[z] + 1], b);
        }
    }
}

extern "C" void kernel_launch(void* const* d_in, const int* in_sizes, int n_in,
                              void* d_out, int out_size, void* d_ws, size_t ws_size,
                              hipStream_t stream) {
    const float* u           = (const float*)d_in[0];
    const float* B           = (const float*)d_in[1];
    const float* Jacc        = (const float*)d_in[2];
    const float* gp_w        = (const float*)d_in[3];
    const int*   conn        = (const int*)  d_in[4];
    const float* weight1     = (const float*)d_in[5];
    const float* scales_inp  = (const float*)d_in[6];
    const float* limits_inp  = (const float*)d_in[7];
    const float* scales_grad = (const float*)d_in[8];
    const float* limits_grad = (const float*)d_in[9];
    const float* W1          = (const float*)d_in[10];
    const float* b1          = (const float*)d_in[11];
    const float* W2          = (const float*)d_in[12];
    const float* b2          = (const float*)d_in[13];
    const float* W3          = (const float*)d_in[14];
    const float* b3          = (const float*)d_in[15];
    float* F = (float*)d_out;
    uint4* wt = (uint4*)d_ws;        // 16 KB weight-fragment table

    (void)hipMemsetAsync(d_out, 0, sizeof(float) * NDOF, stream);

    pack_weights<<<1, 64, 0, stream>>>(W1, b1, W2, wt);

    const int grid = (NELEM + 127) / 128;   // 128 elements (512 GPs) / block
    fem_force_kernel<<<grid, 256, 0, stream>>>(
        u, B, Jacc, gp_w, conn, weight1, scales_inp, limits_inp,
        scales_grad, limits_grad, b2, W3, b3, wt, F);
}

// Round 5
// 446.754 us; speedup vs baseline: 1.0925x; 1.0925x over previous
//
#include <hip/hip_runtime.h>

#define NELEM 500000
#define NDOF 500000
#define HID 64

typedef _Float16 half2v __attribute__((ext_vector_type(2)));
typedef _Float16 half8v __attribute__((ext_vector_type(8)));
typedef float float4v __attribute__((ext_vector_type(4)));

// lambda = 2*log2(e): prescaled into W1,b1,W2,b2 so tanh needs no multiply.
#define LAM 2.885390081777927f

__device__ __forceinline__ half2v pk(float a, float b) {
    return __builtin_bit_cast(half2v, __builtin_amdgcn_cvt_pkrtz(a, b));
}
// tanh(z) with y = LAM*z prescaled. exp2(+-inf) saturates correctly.
__device__ __forceinline__ float tanh2(float y) {
    float e = __builtin_amdgcn_exp2f(y);
    float r = __builtin_amdgcn_rcpf(e + 1.0f);
    return fmaf(-2.0f, r, 1.0f);
}
__device__ __forceinline__ float fdot2(half2v a, half2v b, float c) {
    return __builtin_amdgcn_fdot2(a, b, c, false);
}

// ds_swizzle BitMode: src = ((lane&AND)|OR)^XOR within 32-lane halves.
//   quad broadcast g: 0x1C,0x3C,0x5C,0x7C ; xor16: 0x401F
#define SWZF(x, pat) __builtin_bit_cast(float, \
    __builtin_amdgcn_ds_swizzle(__builtin_bit_cast(int, (x)), (pat)))

// ---- setup kernel 1: pack per-lane weight fragments into workspace ----
// Layout (uint4 units, [frag][lane]):
//   0..3  : w1p (16 half2 = LAM*W1 cols for this lane's quad)
//   4..7  : b1v (16 f32  = LAM*b1)
//   8..15 : bf[t][f] (half8 W2 fragments, frag idx = 8+2t+f)
__global__ __launch_bounds__(64, 1) void pack_weights(
    const float* __restrict__ W1, const float* __restrict__ b1,
    const float* __restrict__ W2, uint4* __restrict__ ws)
{
    const int lane = threadIdx.x & 63;
    const int quad = lane >> 4, l15 = lane & 15;
    union { uint4 q[4]; uint u[16]; } WU;
    union { uint4 q[4]; float f[16]; } BU;
#pragma unroll
    for (int f = 0; f < 2; f++)
#pragma unroll
        for (int j = 0; j < 8; j++) {
            const int k = f * 32 + quad * 8 + j;
            WU.u[f * 8 + j] = __builtin_bit_cast(uint, pk(LAM * W1[k], LAM * W1[HID + k]));
            BU.f[f * 8 + j] = LAM * b1[k];
        }
#pragma unroll
    for (int i = 0; i < 4; i++) {
        ws[i * 64 + lane] = WU.q[i];
        ws[(4 + i) * 64 + lane] = BU.q[i];
    }
#pragma unroll
    for (int t = 0; t < 4; t++)
#pragma unroll
        for (int f = 0; f < 2; f++) {
            union { uint4 q; uint u[4]; } T;
#pragma unroll
            for (int jj = 0; jj < 4; jj++) {
                const int k0 = f * 32 + quad * 8 + 2 * jj;
                const int n  = t * 16 + l15;
                T.u[jj] = __builtin_bit_cast(uint,
                    pk(LAM * W2[k0 * HID + n], LAM * W2[(k0 + 1) * HID + n]));
            }
            ws[(8 + 2 * t + f) * 64 + lane] = T.q;
        }
}

// ---- setup kernel 2: u1 = weight1 * u (kills one random-gather stream) ----
__global__ __launch_bounds__(256, 8) void premul_u(
    const float* __restrict__ u, const float* __restrict__ w1,
    float* __restrict__ u1)
{
    const int i = blockIdx.x * 256 + threadIdx.x;
    if (i < NDOF / 4) {
        const float4 a = ((const float4*)u)[i];
        const float4 b = ((const float4*)w1)[i];
        ((float4*)u1)[i] = make_float4(a.x * b.x, a.y * b.y, a.z * b.z, a.w * b.w);
    }
}

// one layer-2/3 tile step: C=b2 -> 2 MFMA -> tanh -> packed layer-3 partials
#define TSTEP(tt, qa, qb) do { \
    const float4v b2v = *(const float4v*)&b2t[wb + (tt) * 4]; \
    union { uint4 q; uint u[4]; } w3u; \
    w3u.q = *(const uint4*)&w3t[wb + (tt) * 4]; \
    float4v c = b2v; \
    c = __builtin_amdgcn_mfma_f32_16x16x32_f16(__builtin_bit_cast(half8v, (qa)), B0.v, c, 0, 0, 0); \
    c = __builtin_amdgcn_mfma_f32_16x16x32_f16(__builtin_bit_cast(half8v, (qb)), B1.v, c, 0, 0, 0); \
    _Pragma("unroll") \
    for (int reg = 0; reg < 4; reg++) { \
        const float h = tanh2(c[reg]); \
        const half2v hh = pk(h, h); \
        sp = sp + hh * __builtin_bit_cast(half2v, w3u.u[reg]); \
    } \
} while (0)

// 1-elem/thread 3-phase GP kernel. Weights live in PINNED registers
// (opaque asm: allocator cannot remat them back to global — the r3
// demotion), loaded from the packed wt table after phase 1 (r1 lesson).
// b2/W3 live in 256B LDS tables, read per TSTEP behind a zr guard so
// they are never hoisted into 32 held regs. bounds(256,4): cap 128 VGPR,
// occupancy cap 50% (r3's bounds(...,3) was the real 31% limiter).
__global__ __launch_bounds__(256, 4) void fem_force_kernel(
    const float* __restrict__ u, const float* __restrict__ B,
    const float* __restrict__ Jacc, const float* __restrict__ gp_w,
    const int* __restrict__ conn, const float* __restrict__ weight1,
    const float* __restrict__ scales_inp, const float* __restrict__ limits_inp,
    const float* __restrict__ scales_grad, const float* __restrict__ limits_grad,
    const float* __restrict__ b2, const float* __restrict__ W3,
    const float* __restrict__ b3, const uint4* __restrict__ wt,
    const int premul, float* __restrict__ F)
{
    __shared__ uint sX[256];        // packed-f16 (x0,x1) per GP-row
    __shared__ uint sG[256];        // packed-f16 (p,q)  per GP-row
    __shared__ uint sB[256][9];     // packed-f16 (P[j],Q[j]) j=0..7, pad
    __shared__ __align__(16) float b2t[64];
    __shared__ __align__(16) uint  w3t[64];   // pk(W3[2n], W3[2n+1])

    const int tid  = threadIdx.x;
    const int lane = tid & 63;
    const int wv   = tid >> 6;
    const int quad = lane >> 4;
    const int l15  = lane & 15;
    const int g    = tid & 3;        // gauss point of this thread
    const int m    = tid >> 2;       // element slot within block
    const int e    = blockIdx.x * 64 + m;
    const bool valid = (e < NELEM);

    // stage b2 / packed-W3 tables (index i = quad*16 + t*4 + reg)
    if (tid < 128) {
        const int i  = tid & 63;
        const int it = (i >> 2) & 3, iq = i >> 4, ir = i & 3;
        const int n  = it * 16 + iq * 4 + ir;
        if (tid < 64) b2t[i] = LAM * b2[n];
        else          w3t[i] = __builtin_bit_cast(uint, pk(W3[2 * n], W3[2 * n + 1]));
    }

    const float SQ23 = 0.816496580927726f;
    const float si0 = scales_inp[0], si1 = scales_inp[1];
    const float li0 = limits_inp[0], li1 = limits_inp[1];
    const float isg0 = 1.0f / scales_grad[0], isg1 = 1.0f / scales_grad[1];
    const float b30c = b3[0] - limits_grad[0];
    const float b31c = b3[1] - limits_grad[1];

    // ---- phase 1: strain invariants for this thread's GP -> P,Q + x ----
    int nd = 0;
    uint xw = 0u;
    if (valid) {
        nd = conn[4 * e + g];
        const float2 uu = *(const float2*)(u + 2 * nd);
        float vx, vy;
        if (premul) { vx = uu.x; vy = uu.y; }
        else {
            const float2 wv2 = *(const float2*)(weight1 + 2 * nd);
            vx = wv2.x * uu.x; vy = wv2.y * uu.y;
        }
        float ue[8];
        ue[0] = SWZF(vx, 0x1C); ue[1] = SWZF(vy, 0x1C);
        ue[2] = SWZF(vx, 0x3C); ue[3] = SWZF(vy, 0x3C);
        ue[4] = SWZF(vx, 0x5C); ue[5] = SWZF(vy, 0x5C);
        ue[6] = SWZF(vx, 0x7C); ue[7] = SWZF(vy, 0x7C);

        float Bg[24];
        const float4* Bp = (const float4*)(B + (size_t)(e * 4 + g) * 24);
#pragma unroll
        for (int t2 = 0; t2 < 6; t2++) {
            const float4 v = Bp[t2];
            Bg[4 * t2 + 0] = v.x; Bg[4 * t2 + 1] = v.y;
            Bg[4 * t2 + 2] = v.z; Bg[4 * t2 + 3] = v.w;
        }
        float s0 = 0.f, s1 = 0.f, s2 = 0.f;
#pragma unroll
        for (int j = 0; j < 8; j++) {
            s0 = fmaf(Bg[j],      ue[j], s0);
            s1 = fmaf(Bg[8 + j],  ue[j], s1);
            s2 = fmaf(Bg[16 + j], ue[j], s2);
        }
        const float ev  = s0 + s1;
        const float ev3 = ev * (1.0f / 3.0f);
        const float d00 = s0 - ev3, d11 = s1 - ev3, d22 = -ev3, d01 = 0.5f * s2;
        const float det = sqrtf(d00 * d00 + d11 * d11 + d22 * d22 + 2.0f * d01 * d01);
        const float rd  = __builtin_amdgcn_rcpf(det);
        const float es  = det * SQ23;
        const float wgt = Jacc[4 * e + g] * gp_w[g];
        const float sc  = SQ23 * rd * wgt;
        const float c00 = sc * d00, c11 = sc * d11, c01 = sc * d01;
#pragma unroll
        for (int j = 0; j < 8; j++) {
            const float P = wgt * (Bg[j] + Bg[8 + j]);
            const float Q = fmaf(c00, Bg[j], fmaf(c11, Bg[8 + j], c01 * Bg[16 + j]));
            sB[tid][j] = __builtin_bit_cast(uint, pk(P, Q));
        }
        xw = __builtin_bit_cast(uint, pk(fmaf(ev, si0, li0), fmaf(es, si1, li1)));
    }
    sX[tid] = xw;                   // invalid lanes write zeros
    __syncthreads();

    // ---- held weight fragments: 16 coalesced b128 loads, then PINNED ----
    union { uint4 q[4]; uint u[16]; } W1U;
    union { uint4 q[4]; float f[16]; } B1U;
    uint4 bfq[8];
#pragma unroll
    for (int i = 0; i < 4; i++) {
        W1U.q[i] = wt[i * 64 + lane];
        B1U.q[i] = wt[(4 + i) * 64 + lane];
    }
#pragma unroll
    for (int i = 0; i < 8; i++) bfq[i] = wt[(8 + i) * 64 + lane];
    // opaque pin: values become unknown to the compiler -> it must keep
    // them resident in VGPRs (no remat-from-global, the r3 demotion).
#pragma unroll
    for (int i = 0; i < 4; i++) {
        asm volatile("" : "+v"(W1U.q[i].x), "+v"(W1U.q[i].y), "+v"(W1U.q[i].z), "+v"(W1U.q[i].w));
        asm volatile("" : "+v"(B1U.q[i].x), "+v"(B1U.q[i].y), "+v"(B1U.q[i].z), "+v"(B1U.q[i].w));
    }
#pragma unroll
    for (int i = 0; i < 8; i++)
        asm volatile("" : "+v"(bfq[i].x), "+v"(bfq[i].y), "+v"(bfq[i].z), "+v"(bfq[i].w));

    // ---- phase 2: wave-level MFMA MLP over this wave's 64 GP-rows ----
    int zr = 0;                     // opaque zero: keeps b2t/w3t reads in-loop
#pragma unroll 1
    for (int rt = 0; rt < 4; rt++) {
        asm volatile("" : "+v"(zr));
        const int wb = quad * 16 + zr;
        const int tb = wv * 64 + rt * 16;
        const half2v xp = __builtin_bit_cast(half2v, sX[tb + l15]);

        // layer 1 -> h1 fragments (B operand of swapped MFMA)
        union { half8v v; uint uu[4]; } B0, B1;
#pragma unroll
        for (int jj = 0; jj < 4; jj++) {
            const float t0 = tanh2(fdot2(xp, __builtin_bit_cast(half2v, W1U.u[2 * jj]),     B1U.f[2 * jj]));
            const float t1 = tanh2(fdot2(xp, __builtin_bit_cast(half2v, W1U.u[2 * jj + 1]), B1U.f[2 * jj + 1]));
            const float t2 = tanh2(fdot2(xp, __builtin_bit_cast(half2v, W1U.u[8 + 2 * jj]),     B1U.f[8 + 2 * jj]));
            const float t3 = tanh2(fdot2(xp, __builtin_bit_cast(half2v, W1U.u[8 + 2 * jj + 1]), B1U.f[8 + 2 * jj + 1]));
            B0.uu[jj] = __builtin_bit_cast(uint, pk(t0, t1));
            B1.uu[jj] = __builtin_bit_cast(uint, pk(t2, t3));
        }

        // layer 2 (8 MFMA) + packed-f16 layer-3 partials
        half2v sp = {_Float16(0.f), _Float16(0.f)};
        TSTEP(0, bfq[0], bfq[1]);
        TSTEP(1, bfq[2], bfq[3]);
        TSTEP(2, bfq[4], bfq[5]);
        TSTEP(3, bfq[6], bfq[7]);

        // f32 reduce over the 4 quads (hidden axis): xor16 then xor32
        float s0 = (float)sp[0], s1 = (float)sp[1];
        s0 += SWZF(s0, 0x401F);
        s1 += SWZF(s1, 0x401F);
        s0 += __shfl_xor(s0, 32, 64);
        s1 += __shfl_xor(s1, 32, 64);
        if (quad == 0) {
            const float p = (s0 + b30c) * isg0;
            const float q = (s1 + b31c) * isg1;
            sG[tb + l15] = __builtin_bit_cast(uint, pk(p, q));
        }
    }
    __syncthreads();

    // ---- phase 3: EP pair via fdot2 of (p,q)x(P,Q), 2 atomics ----
    if (valid) {
        const int rb = tid & ~3;
        float a = 0.f, b = 0.f;
#pragma unroll
        for (int gp = 0; gp < 4; gp++) {
            const half2v pq = __builtin_bit_cast(half2v, sG[rb + gp]);
            const half2v w0 = __builtin_bit_cast(half2v, sB[rb + gp][2 * g]);
            const half2v w1 = __builtin_bit_cast(half2v, sB[rb + gp][2 * g + 1]);
            a = fdot2(pq, w0, a);
            b = fdot2(pq, w1, b);
        }
        atomicAdd(&F[2 * nd],     a);
        atomicAdd(&F[2 * nd + 1], b);
    }
}

extern "C" void kernel_launch(void* const* d_in, const int* in_sizes, int n_in,
                              void* d_out, int out_size, void* d_ws, size_t ws_size,
                              hipStream_t stream) {
    const float* u           = (const float*)d_in[0];
    const float* B           = (const float*)d_in[1];
    const float* Jacc        = (const float*)d_in[2];
    const float* gp_w        = (const float*)d_in[3];
    const int*   conn        = (const int*)  d_in[4];
    const float* weight1     = (const float*)d_in[5];
    const float* scales_inp  = (const float*)d_in[6];
    const float* limits_inp  = (const float*)d_in[7];
    const float* scales_grad = (const float*)d_in[8];
    const float* limits_grad = (const float*)d_in[9];
    const float* W1          = (const float*)d_in[10];
    const float* b1          = (const float*)d_in[11];
    const float* W2          = (const float*)d_in[12];
    const float* b2          = (const float*)d_in[13];
    const float* W3          = (const float*)d_in[14];
    const float* b3          = (const float*)d_in[15];
    float* F = (float*)d_out;

    uint4* wt = (uint4*)d_ws;                       // 16 KB weight table
    float* u1 = (float*)((char*)d_ws + 16384);      // 2 MB premultiplied u
    const int can_premul = (ws_size >= 16384 + sizeof(float) * NDOF) ? 1 : 0;

    (void)hipMemsetAsync(d_out, 0, sizeof(float) * NDOF, stream);

    pack_weights<<<1, 64, 0, stream>>>(W1, b1, W2, wt);
    if (can_premul)
        premul_u<<<(NDOF / 4 + 255) / 256, 256, 0, stream>>>(u, weight1, u1);

    const int grid = (NELEM + 63) / 64;             // 64 elems / block
    fem_force_kernel<<<grid, 256, 0, stream>>>(
        can_premul ? u1 : u, B, Jacc, gp_w, conn, weight1,
        scales_inp, limits_inp, scales_grad, limits_grad,
        b2, W3, b3, wt, can_premul, F);
}